// Round 19
// baseline (78.104 us; speedup 1.0000x reference)
//
#include <hip/hip_runtime.h>
#include <hip/hip_bf16.h>

#define S_LEN 2048
#define DH    64
#define QB    128
#define KB    64
#define BHN   64
#define NQT   16
#define LDS_STRIDE 72   // fallback kernel only

typedef __attribute__((ext_vector_type(8))) short short8;
typedef __attribute__((ext_vector_type(4))) float f32x4;

union Frag {
  short8   s;
  unsigned u[4];
};

// RNE float pair -> packed bf16x2 (compiler emits v_cvt_pk_bf16_f32)
__device__ __forceinline__ unsigned pack2(float a, float b) {
  __hip_bfloat162 h2 = __float22bfloat162_rn(make_float2(a, b));
  unsigned u; __builtin_memcpy(&u, &h2, 4);
  return u;
}

// =====================================================================
// Pre-pass: convert K and V^T to bf16 in MFMA *fragment order*.
// =====================================================================
__global__ __launch_bounds__(256, 2)
void repack(const float* __restrict__ Kg, const float* __restrict__ Vg,
            short* __restrict__ ws) {
  const int bt = blockIdx.x;           // 0..2047: bh = bt>>5, t = bt&31
  const int tid = threadIdx.x;
  const size_t tilebase = (size_t)bt * (64 * 64);
  short* kout = ws + (size_t)bt * 4096;
  short* vout = ws + 8388608 + (size_t)bt * 4096;

#pragma unroll
  for (int it = 0; it < 2; ++it) {
    const int c2 = tid + it * 256;
    const int f = c2 >> 6, l = c2 & 63;
    const int kkh = f >> 2, hi = (f >> 1) & 1, cc = f & 1;
    const int row = kkh * 32 + hi * 16 + (l & 15);
    const int col = cc * 32 + (l >> 4) * 8;
    const float* src = Kg + tilebase + row * 64 + col;
    float4 a = *(const float4*)src, b = *(const float4*)(src + 4);
    Frag w;
    w.u[0] = pack2(a.x, a.y); w.u[1] = pack2(a.z, a.w);
    w.u[2] = pack2(b.x, b.y); w.u[3] = pack2(b.z, b.w);
    *(short8*)(kout + f * 512 + l * 8) = w.s;
  }

  __shared__ float vt[64 * 65];
#pragma unroll
  for (int it = 0; it < 4; ++it) {
    const int i = tid + it * 256;
    const int r = i >> 4, c4 = i & 15;
    float4 x = *(const float4*)(Vg + tilebase + r * 64 + c4 * 4);
    vt[r * 65 + c4 * 4 + 0] = x.x; vt[r * 65 + c4 * 4 + 1] = x.y;
    vt[r * 65 + c4 * 4 + 2] = x.z; vt[r * 65 + c4 * 4 + 3] = x.w;
  }
  __syncthreads();
#pragma unroll
  for (int it = 0; it < 2; ++it) {
    const int v2 = tid + it * 256;
    const int v = v2 >> 6, l = v2 & 63;
    const int kkh = v >> 2, n = v & 3;
    const int d = n * 16 + (l & 15);
    const int k0c = kkh * 32 + (l >> 4) * 8;
    Frag w;
#pragma unroll
    for (int jj = 0; jj < 4; ++jj)
      w.u[jj] = pack2(vt[(k0c + 2 * jj) * 65 + d], vt[(k0c + 2 * jj + 1) * 65 + d]);
    *(short8*)(vout + v * 512 + l * 8) = w.s;
  }
}

// =====================================================================
// Main kernel: 1 wave per block, 64 q-rows per wave, registers only.
// No LDS, no barriers. K double-buffered; V loaded per-phase.
// QK acc seeded with 1.0 -> t = 1+s; p' = t^2+1 = 2p (factor cancels).
// Denominator accumulated on the VALU (dsum), reduced in the epilogue.
// =====================================================================
#define KLOAD(P, t_)                                                           \
  do {                                                                         \
    const short* g_ = gkb + (size_t)(t_) * 4096;                               \
    P##0 = *(const short8*)(g_ + 0 * 512);                                     \
    P##1 = *(const short8*)(g_ + 1 * 512);                                     \
    P##2 = *(const short8*)(g_ + 2 * 512);                                     \
    P##3 = *(const short8*)(g_ + 3 * 512);                                     \
    P##4 = *(const short8*)(g_ + 4 * 512);                                     \
    P##5 = *(const short8*)(g_ + 5 * 512);                                     \
    P##6 = *(const short8*)(g_ + 6 * 512);                                     \
    P##7 = *(const short8*)(g_ + 7 * 512);                                     \
  } while (0)

#define VLOAD(t_)                                                              \
  do {                                                                         \
    const short* g_ = gvb + (size_t)(t_) * 4096;                               \
    vf0 = *(const short8*)(g_ + 0 * 512);                                      \
    vf1 = *(const short8*)(g_ + 1 * 512);                                      \
    vf2 = *(const short8*)(g_ + 2 * 512);                                      \
    vf3 = *(const short8*)(g_ + 3 * 512);                                      \
    vf4 = *(const short8*)(g_ + 4 * 512);                                      \
    vf5 = *(const short8*)(g_ + 5 * 512);                                      \
    vf6 = *(const short8*)(g_ + 6 * 512);                                      \
    vf7 = *(const short8*)(g_ + 7 * 512);                                      \
  } while (0)

// One 32-k chunk (KK = 0 or 32) of one KV tile, all 4 hq sub-tiles.
#define BODYK(K0, K1, K2, K3, V0, V1, V2, V3, t_, KK, MASKED_)                 \
  do {                                                                         \
    const int k0_ = (t_) * KB + (KK);                                          \
    _Pragma("unroll")                                                          \
    for (int hq = 0; hq < 4; ++hq) {                                           \
      f32x4 stL = onesf, stH = onesf;                                          \
      stL = __builtin_amdgcn_mfma_f32_16x16x32_bf16(K0, qf[hq][0].s, stL, 0, 0, 0); \
      stL = __builtin_amdgcn_mfma_f32_16x16x32_bf16(K1, qf[hq][1].s, stL, 0, 0, 0); \
      stH = __builtin_amdgcn_mfma_f32_16x16x32_bf16(K2, qf[hq][0].s, stH, 0, 0, 0); \
      stH = __builtin_amdgcn_mfma_f32_16x16x32_bf16(K3, qf[hq][1].s, stH, 0, 0, 0); \
      const int qrow = qbase + hq * 16 + qid;                                  \
      float pl[4], ph[4];                                                      \
      _Pragma("unroll")                                                        \
      for (int r = 0; r < 4; ++r) {                                            \
        float tl = stL[r], th = stH[r];                                        \
        pl[r] = fmaf(tl, tl, 1.0f);   /* p' = (1+s)^2 + 1 = 2p */              \
        ph[r] = fmaf(th, th, 1.0f);                                            \
        if (MASKED_) {                                                         \
          if (k0_ + 4 * g + r > qrow)      pl[r] = 0.f;                        \
          if (k0_ + 16 + 4 * g + r > qrow) ph[r] = 0.f;                        \
        }                                                                      \
        dsum[hq] += pl[r] + ph[r];                                             \
      }                                                                        \
      unsigned w0 = pack2(pl[0], pl[1]);                                       \
      unsigned w1 = pack2(pl[2], pl[3]);                                       \
      unsigned w2 = pack2(ph[0], ph[1]);                                       \
      unsigned w3 = pack2(ph[2], ph[3]);                                       \
      Frag pa;                                                                 \
      {                                                                        \
        auto sA32 = __builtin_amdgcn_permlane32_swap(w0, w2, false, false);    \
        auto sA16 = __builtin_amdgcn_permlane16_swap(sA32[0], sA32[1], false, false); \
        auto sB32 = __builtin_amdgcn_permlane32_swap(w1, w3, false, false);    \
        auto sB16 = __builtin_amdgcn_permlane16_swap(sB32[0], sB32[1], false, false); \
        pa.u[0] = (unsigned)sA16[0];                                           \
        pa.u[2] = (unsigned)sA16[1];                                           \
        pa.u[1] = (unsigned)sB16[0];                                           \
        pa.u[3] = (unsigned)sB16[1];                                           \
      }                                                                        \
      acc[hq][0] = __builtin_amdgcn_mfma_f32_16x16x32_bf16(pa.s, V0, acc[hq][0], 0, 0, 0); \
      acc[hq][1] = __builtin_amdgcn_mfma_f32_16x16x32_bf16(pa.s, V1, acc[hq][1], 0, 0, 0); \
      acc[hq][2] = __builtin_amdgcn_mfma_f32_16x16x32_bf16(pa.s, V2, acc[hq][2], 0, 0, 0); \
      acc[hq][3] = __builtin_amdgcn_mfma_f32_16x16x32_bf16(pa.s, V3, acc[hq][3], 0, 0, 0); \
    }                                                                          \
  } while (0)

#define BODY(P, t_, MASKED_)                                                   \
  do {                                                                         \
    BODYK(P##0, P##1, P##2, P##3, vf0, vf1, vf2, vf3, t_, 0,  MASKED_);        \
    BODYK(P##4, P##5, P##6, P##7, vf4, vf5, vf6, vf7, t_, 32, MASKED_);        \
  } while (0)

__global__ __launch_bounds__(64)
void based_wave(const float* __restrict__ Qg, const short* __restrict__ Fr,
                float* __restrict__ Og) {
  const int lane = threadIdx.x;        // 64-thread block = 1 wave
  const int qid  = lane & 15;
  const int g    = lane >> 4;

  const int bh = blockIdx.x;           // linear%8 = bh%8 -> XCD-local
  const int y  = blockIdx.y;           // 0..31
  // balanced rounds: each dispatch round of 256 blocks covers j-quads
  // {0,31,1,30},... with equal total tile count.
  const int j  = (y & 1) ? (31 - (y >> 1)) : (y >> 1);   // 64-row subtile 0..31
  const int qbase = j * 64;

  const size_t base = (size_t)bh * S_LEN;
  const short* gkb = Fr + ((size_t)(bh << 5) << 12) + lane * 8;
  const short* gvb = gkb + 8388608;

  const f32x4 onesf = (f32x4){1.f, 1.f, 1.f, 1.f};  // QK seed -> t = 1+s

  // ---- Q fragments for 64 rows, pre-scaled by 1/sqrt(D)=0.125 ----
  Frag qf[4][2];
  {
    const float SC = 0.125f;
#pragma unroll
    for (int hq = 0; hq < 4; ++hq) {
      const int qrow = qbase + hq * 16 + qid;
      const float* qp = Qg + (base + qrow) * DH + g * 8;
#pragma unroll
      for (int c = 0; c < 2; ++c) {
        float4 f0 = *(const float4*)(qp + c * 32);
        float4 f1 = *(const float4*)(qp + c * 32 + 4);
        qf[hq][c].u[0] = pack2(f0.x * SC, f0.y * SC);
        qf[hq][c].u[1] = pack2(f0.z * SC, f0.w * SC);
        qf[hq][c].u[2] = pack2(f1.x * SC, f1.y * SC);
        qf[hq][c].u[3] = pack2(f1.z * SC, f1.w * SC);
      }
    }
  }

  f32x4 acc[4][4];
  float dsum[4];
#pragma unroll
  for (int hq = 0; hq < 4; ++hq) {
    dsum[hq] = 0.f;
#pragma unroll
    for (int n = 0; n < 4; ++n) acc[hq][n] = (f32x4){0.f, 0.f, 0.f, 0.f};
  }

  const int nfull = j;                 // tiles 0..j-1 full; tile j masked

  short8 ka0, ka1, ka2, ka3, ka4, ka5, ka6, ka7;   // K dbuf A
  short8 kb0, kb1, kb2, kb3, kb4, kb5, kb6, kb7;   // K dbuf B
  short8 vf0, vf1, vf2, vf3, vf4, vf5, vf6, vf7;   // V current tile

  KLOAD(ka, 0);
  int t = 0;
  if (nfull & 1) {                     // peel one so the loop body is even
    KLOAD(kb, 1);
    VLOAD(0);
    BODY(ka, 0, 0);
    ka0 = kb0; ka1 = kb1; ka2 = kb2; ka3 = kb3;    // one-time role copy
    ka4 = kb4; ka5 = kb5; ka6 = kb6; ka7 = kb7;
    t = 1;
  }
  for (; t + 1 < nfull; t += 2) {
    KLOAD(kb, t + 1);
    VLOAD(t);
    BODY(ka, t, 0);
    KLOAD(ka, t + 2);                  // t+2 <= nfull = j -> always valid
    VLOAD(t + 1);
    BODY(kb, t + 1, 0);
  }
  // t == nfull here; kA holds tile j (the diagonal, masked)
  VLOAD(nfull);
  BODY(ka, nfull, 1);

  // ---- denominator reduction: sum the 4 g-groups per q column ----
  float dred[4];
#pragma unroll
  for (int hq = 0; hq < 4; ++hq) {
    float v = dsum[hq];
    v += __shfl_xor(v, 16);
    v += __shfl_xor(v, 32);
    dred[hq] = v;                      // lane l holds denom(q = hq*16 + (l&15))
  }

  // ---- normalize and store fp32 (p' = 2p: eps doubles, ratio exact) ----
#pragma unroll
  for (int hq = 0; hq < 4; ++hq) {
#pragma unroll
    for (int r = 0; r < 4; ++r) {
      float dn  = __shfl(dred[hq], 4 * g + r);   // lane with (l&15)==4g+r
      float inv = 1.0f / (dn + 2e-6f);
      const int row = qbase + hq * 16 + 4 * g + r;
      float* op = Og + (base + row) * DH + qid;
#pragma unroll
      for (int n = 0; n < 4; ++n) op[n * 16] = acc[hq][n][r] * inv;
    }
  }
}

// =====================================================================
// Fallback (R8 kernel, verified): used only if ws_size < 32 MB.
// =====================================================================
#define STAGE_LOAD(k0_)                                                        \
  do {                                                                         \
    if (tid < 128) {                                                           \
      const float4* ksrc = (const float4*)(Kg + (base + (size_t)(k0_)) * DH); \
      r0 = ksrc[tid];       r1 = ksrc[tid + 128];                              \
      r2 = ksrc[tid + 256]; r3 = ksrc[tid + 384];                              \
      r4 = ksrc[tid + 512]; r5 = ksrc[tid + 640];                              \
      r6 = ksrc[tid + 768]; r7 = ksrc[tid + 896];                              \
    } else {                                                                   \
      const float4* vsrc = (const float4*)(Vg + (base + (size_t)(k0_)) * DH)  \
                           + ((tid - 128) >> 4) * 128 + ((tid - 128) & 15);    \
      r0 = vsrc[0];  r1 = vsrc[16]; r2 = vsrc[32]; r3 = vsrc[48];              \
      r4 = vsrc[64]; r5 = vsrc[80]; r6 = vsrc[96]; r7 = vsrc[112];             \
    }                                                                          \
  } while (0)

#define STAGE_WRITE(b_)                                                        \
  do {                                                                         \
    if (tid < 128) {                                                           \
      short* Kd = Klds[b_];                                                    \
      const int rb = tid >> 4, c4 = tid & 15;                                  \
      *(uint2*)&Kd[(rb + 0)  * LDS_STRIDE + c4 * 4] = make_uint2(pack2(r0.x, r0.y), pack2(r0.z, r0.w)); \
      *(uint2*)&Kd[(rb + 8)  * LDS_STRIDE + c4 * 4] = make_uint2(pack2(r1.x, r1.y), pack2(r1.z, r1.w)); \
      *(uint2*)&Kd[(rb + 16) * LDS_STRIDE + c4 * 4] = make_uint2(pack2(r2.x, r2.y), pack2(r2.z, r2.w)); \
      *(uint2*)&Kd[(rb + 24) * LDS_STRIDE + c4 * 4] = make_uint2(pack2(r3.x, r3.y), pack2(r3.z, r3.w)); \
      *(uint2*)&Kd[(rb + 32) * LDS_STRIDE + c4 * 4] = make_uint2(pack2(r4.x, r4.y), pack2(r4.z, r4.w)); \
      *(uint2*)&Kd[(rb + 40) * LDS_STRIDE + c4 * 4] = make_uint2(pack2(r5.x, r5.y), pack2(r5.z, r5.w)); \
      *(uint2*)&Kd[(rb + 48) * LDS_STRIDE + c4 * 4] = make_uint2(pack2(r6.x, r6.y), pack2(r6.z, r6.w)); \
      *(uint2*)&Kd[(rb + 56) * LDS_STRIDE + c4 * 4] = make_uint2(pack2(r7.x, r7.y), pack2(r7.z, r7.w)); \
    } else {                                                                   \
      short* Vd = Vlds[b_];                                                    \
      const int l = tid - 128, c4 = l & 15, rp = l >> 4;                       \
      const int slot = (rp + (c4 & 7)) & 7;                                    \
      short* vp = &Vd[(c4 * 4) * LDS_STRIDE + slot * 8];                       \
      Frag w;                                                                  \
      w.u[0] = pack2(r0.x, r1.x); w.u[1] = pack2(r2.x, r3.x);                  \
      w.u[2] = pack2(r4.x, r5.x); w.u[3] = pack2(r6.x, r7.x);                  \
      *(short8*)&vp[0 * LDS_STRIDE] = w.s;                                     \
      w.u[0] = pack2(r0.y, r1.y); w.u[1] = pack2(r2.y, r3.y);                  \
      w.u[2] = pack2(r4.y, r5.y); w.u[3] = pack2(r6.y, r7.y);                  \
      *(short8*)&vp[1 * LDS_STRIDE] = w.s;                                     \
      w.u[0] = pack2(r0.z, r1.z); w.u[1] = pack2(r2.z, r3.z);                  \
      w.u[2] = pack2(r4.z, r5.z); w.u[3] = pack2(r6.z, r7.z);                  \
      *(short8*)&vp[2 * LDS_STRIDE] = w.s;                                     \
      w.u[0] = pack2(r0.w, r1.w); w.u[1] = pack2(r2.w, r3.w);                  \
      w.u[2] = pack2(r4.w, r5.w); w.u[3] = pack2(r6.w, r7.w);                  \
      *(short8*)&vp[3 * LDS_STRIDE] = w.s;                                     \
    }                                                                          \
  } while (0)

#define COMPUTE_TILE(KbP_, VbP_, k0_, MASKED_)                                 \
  do {                                                                         \
    const short* Kb = (KbP_);                                                  \
    const short* Vb = (VbP_);                                                  \
    _Pragma("unroll")                                                          \
    for (int kk = 0; kk < KB; kk += 32) {                                      \
      if (!(MASKED_) || (q0 + wv * 32 + 31 >= (k0_) + kk)) {                   \
        short8 aLo[2], aHi[2];                                                 \
        _Pragma("unroll")                                                      \
        for (int c = 0; c < 2; ++c) {                                          \
          aLo[c] = *(const short8*)&Kb[(kk + qid) * LDS_STRIDE + c * 32 + g * 8];        \
          aHi[c] = *(const short8*)&Kb[(kk + 16 + qid) * LDS_STRIDE + c * 32 + g * 8];   \
        }                                                                      \
        f32x4 stL[2], stH[2];                                                  \
        _Pragma("unroll")                                                      \
        for (int hq = 0; hq < 2; ++hq) {                                       \
          stL[hq] = (f32x4){0.f, 0.f, 0.f, 0.f};                               \
          stH[hq] = (f32x4){0.f, 0.f, 0.f, 0.f};                               \
          _Pragma("unroll")                                                    \
          for (int c = 0; c < 2; ++c) {                                        \
            stL[hq] = __builtin_amdgcn_mfma_f32_16x16x32_bf16(aLo[c], qf[hq][c].s, stL[hq], 0, 0, 0); \
            stH[hq] = __builtin_amdgcn_mfma_f32_16x16x32_bf16(aHi[c], qf[hq][c].s, stH[hq], 0, 0, 0); \
          }                                                                    \
        }                                                                      \
        unsigned wrd[2][4];                                                    \
        _Pragma("unroll")                                                      \
        for (int hq = 0; hq < 2; ++hq) {                                       \
          const int qrow = q0 + wv * 32 + hq * 16 + qid;                       \
          float pl[4], ph[4];                                                  \
          _Pragma("unroll")                                                    \
          for (int r = 0; r < 4; ++r) {                                        \
            float sl = stL[hq][r], sh = stH[hq][r];                            \
            pl[r] = fmaf(sl, fmaf(sl, 0.5f, 1.0f), 1.0f);                      \
            ph[r] = fmaf(sh, fmaf(sh, 0.5f, 1.0f), 1.0f);                      \
            if (MASKED_) {                                                     \
              if ((k0_) + kk + 4 * g + r > qrow)      pl[r] = 0.f;             \
              if ((k0_) + kk + 16 + 4 * g + r > qrow) ph[r] = 0.f;             \
            }                                                                  \
          }                                                                    \
          wrd[hq][0] = pack2(pl[0], pl[1]);                                    \
          wrd[hq][1] = pack2(pl[2], pl[3]);                                    \
          wrd[hq][2] = pack2(ph[0], ph[1]);                                    \
          wrd[hq][3] = pack2(ph[2], ph[3]);                                    \
        }                                                                      \
        Frag pa[2];                                                            \
        _Pragma("unroll")                                                      \
        for (int hq = 0; hq < 2; ++hq) {                                       \
          auto sA32 = __builtin_amdgcn_permlane32_swap(wrd[hq][0], wrd[hq][2], false, false); \
          auto sA16 = __builtin_amdgcn_permlane16_swap(sA32[0], sA32[1], false, false);       \
          auto sB32 = __builtin_amdgcn_permlane32_swap(wrd[hq][1], wrd[hq][3], false, false); \
          auto sB16 = __builtin_amdgcn_permlane16_swap(sB32[0], sB32[1], false, false);       \
          pa[hq].u[0] = (unsigned)sA16[0];                                     \
          pa[hq].u[2] = (unsigned)sA16[1];                                     \
          pa[hq].u[1] = (unsigned)sB16[0];                                     \
          pa[hq].u[3] = (unsigned)sB16[1];                                     \
        }                                                                      \
        _Pragma("unroll")                                                      \
        for (int n = 0; n < 4; ++n) {                                          \
          const int row = n * 16 + qid;                                        \
          const int un  = ((kk >> 3) + g + ((row >> 2) & 7)) & 7;              \
          short8 vb = *(const short8*)&Vb[row * LDS_STRIDE + un * 8];          \
          acc[0][n] = __builtin_amdgcn_mfma_f32_16x16x32_bf16(pa[0].s, vb, acc[0][n], 0, 0, 0); \
          acc[1][n] = __builtin_amdgcn_mfma_f32_16x16x32_bf16(pa[1].s, vb, acc[1][n], 0, 0, 0); \
        }                                                                      \
        dacc[0] = __builtin_amdgcn_mfma_f32_16x16x32_bf16(pa[0].s, ones.s, dacc[0], 0, 0, 0);   \
        dacc[1] = __builtin_amdgcn_mfma_f32_16x16x32_bf16(pa[1].s, ones.s, dacc[1], 0, 0, 0);   \
      }                                                                        \
    }                                                                          \
  } while (0)

__global__ __launch_bounds__(256, 2)
void based_attn(const float* __restrict__ Qg,
                const float* __restrict__ Kg,
                const float* __restrict__ Vg,
                float* __restrict__ Og) {
  const int tid  = threadIdx.x;
  const int lane = tid & 63;
  const int wv   = tid >> 6;
  const int qid  = lane & 15;
  const int g    = lane >> 4;

  const int bh = blockIdx.x;
  const int qy = blockIdx.y;

  __shared__ short Klds[2][KB * LDS_STRIDE];
  __shared__ short Vlds[2][DH * LDS_STRIDE];

  const size_t base = (size_t)bh * S_LEN;

  Frag ones;
  {
    const unsigned ov = (qid == 0) ? 0x3F803F80u : 0u;
    ones.u[0] = ov; ones.u[1] = ov; ones.u[2] = ov; ones.u[3] = ov;
  }

  float4 r0, r1, r2, r3, r4, r5, r6, r7;

#pragma unroll 1
  for (int half = 0; half < 2; ++half) {
    const int qt = half ? (NQT - 1 - qy) : qy;
    const int q0 = qt * QB;

    Frag qf[2][2];
    {
      const float SC = 0.125f;
#pragma unroll
      for (int hq = 0; hq < 2; ++hq) {
        const int qrow = q0 + wv * 32 + hq * 16 + qid;
        const float* qp = Qg + (base + qrow) * DH + g * 8;
#pragma unroll
        for (int c = 0; c < 2; ++c) {
          float4 f0 = *(const float4*)(qp + c * 32);
          float4 f1 = *(const float4*)(qp + c * 32 + 4);
          qf[hq][c].u[0] = pack2(f0.x * SC, f0.y * SC);
          qf[hq][c].u[1] = pack2(f0.z * SC, f0.w * SC);
          qf[hq][c].u[2] = pack2(f1.x * SC, f1.y * SC);
          qf[hq][c].u[3] = pack2(f1.z * SC, f1.w * SC);
        }
      }
    }

    f32x4 acc[2][4];
    f32x4 dacc[2];
#pragma unroll
    for (int hq = 0; hq < 2; ++hq) {
      dacc[hq] = (f32x4){0.f, 0.f, 0.f, 0.f};
#pragma unroll
      for (int n = 0; n < 4; ++n) acc[hq][n] = (f32x4){0.f, 0.f, 0.f, 0.f};
    }

    STAGE_LOAD(0);
    STAGE_WRITE(0);
    __syncthreads();

    const int nfull = 2 * qt;
    for (int t = 0; t < nfull; ++t) {
      STAGE_LOAD((t + 1) * KB);
      COMPUTE_TILE(Klds[t & 1], Vlds[t & 1], t * KB, 0);
      STAGE_WRITE((t + 1) & 1);
      __syncthreads();
    }
    {
      int t = nfull;
      STAGE_LOAD((t + 1) * KB);
      COMPUTE_TILE(Klds[t & 1], Vlds[t & 1], t * KB, 1);
      STAGE_WRITE((t + 1) & 1);
      __syncthreads();
      t = nfull + 1;
      COMPUTE_TILE(Klds[t & 1], Vlds[t & 1], t * KB, 1);
    }

#pragma unroll
    for (int hq = 0; hq < 2; ++hq) {
#pragma unroll
      for (int r = 0; r < 4; ++r) {
        float dn  = __shfl(dacc[hq][r], 16 * g);
        float inv = 1.0f / (dn + 1e-6f);
        const int row = q0 + wv * 32 + hq * 16 + 4 * g + r;
        float* op = Og + (base + row) * DH + qid;
#pragma unroll
        for (int n = 0; n < 4; ++n) op[n * 16] = acc[hq][n][r] * inv;
      }
    }
  }
}

extern "C" void kernel_launch(void* const* d_in, const int* in_sizes, int n_in,
                              void* d_out, int out_size, void* d_ws, size_t ws_size,
                              hipStream_t stream) {
  (void)in_sizes; (void)n_in; (void)out_size;
  const float* Q = (const float*)d_in[0];
  const float* K = (const float*)d_in[1];
  const float* V = (const float*)d_in[2];
  float* O = (float*)d_out;

  if (ws_size >= (size_t)33554432) {
    short* ws = (short*)d_ws;
    repack<<<dim3(2048), 256, 0, stream>>>(K, V, ws);
    based_wave<<<dim3(64, 32), 64, 0, stream>>>(Q, ws, O);
  } else {
    dim3 grid(BHN, NQT / 2);
    based_attn<<<grid, 256, 0, stream>>>(Q, K, V, O);
  }
}

// Round 20
// 64.387 us; speedup vs baseline: 1.2131x; 1.2131x over previous
//
#include <hip/hip_runtime.h>
#include <hip/hip_bf16.h>

#define S_LEN 2048
#define DH    64
#define QB    128
#define KB    64
#define BHN   64
#define NQT   16
#define LDS_STRIDE 72   // fallback kernel only

typedef __attribute__((ext_vector_type(8))) short short8;
typedef __attribute__((ext_vector_type(4))) float f32x4;

union Frag {
  short8   s;
  unsigned u[4];
};

// RNE float pair -> packed bf16x2 (compiler emits v_cvt_pk_bf16_f32)
__device__ __forceinline__ unsigned pack2(float a, float b) {
  __hip_bfloat162 h2 = __float22bfloat162_rn(make_float2(a, b));
  unsigned u; __builtin_memcpy(&u, &h2, 4);
  return u;
}

// =====================================================================
// Pre-pass: convert K and V^T to bf16 in MFMA *fragment order*.
// =====================================================================
__global__ __launch_bounds__(256, 2)
void repack(const float* __restrict__ Kg, const float* __restrict__ Vg,
            short* __restrict__ ws) {
  const int bt = blockIdx.x;           // 0..2047: bh = bt>>5, t = bt&31
  const int tid = threadIdx.x;
  const size_t tilebase = (size_t)bt * (64 * 64);
  short* kout = ws + (size_t)bt * 4096;
  short* vout = ws + 8388608 + (size_t)bt * 4096;

#pragma unroll
  for (int it = 0; it < 2; ++it) {
    const int c2 = tid + it * 256;
    const int f = c2 >> 6, l = c2 & 63;
    const int kkh = f >> 2, hi = (f >> 1) & 1, cc = f & 1;
    const int row = kkh * 32 + hi * 16 + (l & 15);
    const int col = cc * 32 + (l >> 4) * 8;
    const float* src = Kg + tilebase + row * 64 + col;
    float4 a = *(const float4*)src, b = *(const float4*)(src + 4);
    Frag w;
    w.u[0] = pack2(a.x, a.y); w.u[1] = pack2(a.z, a.w);
    w.u[2] = pack2(b.x, b.y); w.u[3] = pack2(b.z, b.w);
    *(short8*)(kout + f * 512 + l * 8) = w.s;
  }

  __shared__ float vt[64 * 65];
#pragma unroll
  for (int it = 0; it < 4; ++it) {
    const int i = tid + it * 256;
    const int r = i >> 4, c4 = i & 15;
    float4 x = *(const float4*)(Vg + tilebase + r * 64 + c4 * 4);
    vt[r * 65 + c4 * 4 + 0] = x.x; vt[r * 65 + c4 * 4 + 1] = x.y;
    vt[r * 65 + c4 * 4 + 2] = x.z; vt[r * 65 + c4 * 4 + 3] = x.w;
  }
  __syncthreads();
#pragma unroll
  for (int it = 0; it < 2; ++it) {
    const int v2 = tid + it * 256;
    const int v = v2 >> 6, l = v2 & 63;
    const int kkh = v >> 2, n = v & 3;
    const int d = n * 16 + (l & 15);
    const int k0c = kkh * 32 + (l >> 4) * 8;
    Frag w;
#pragma unroll
    for (int jj = 0; jj < 4; ++jj)
      w.u[jj] = pack2(vt[(k0c + 2 * jj) * 65 + d], vt[(k0c + 2 * jj + 1) * 65 + d]);
    *(short8*)(vout + v * 512 + l * 8) = w.s;
  }
}

// =====================================================================
// Main kernel: 2-deep LDS ring (32 KB), ONE tile per barrier (race-free:
// PHASE(t) reads slot t&1, DSWRITE(t+1) writes slot (t+1)&1 only).
// Hoisted per-lane base pointers; QK acc seeded with 1.0 (p' = 2p).
// =====================================================================
#define GLOAD2(t_, T0, T1, T2, T3)                                             \
  do {                                                                         \
    const short* g_ = gk + (size_t)(t_) * 4096;                                \
    T0 = *(const short8*)(g_ + 0 * 512);                                       \
    T1 = *(const short8*)(g_ + 1 * 512);                                       \
    T2 = *(const short8*)(g_ + 2 * 512);                                       \
    T3 = *(const short8*)(g_ + 3 * 512);                                       \
  } while (0)

#define DSWRITE2(t_, T0, T1, T2, T3)                                           \
  do {                                                                         \
    short* w_ = wr + ((t_) & 1) * 8192;                                        \
    *(short8*)(w_ + 0 * 512) = T0;                                             \
    *(short8*)(w_ + 1 * 512) = T1;                                             \
    *(short8*)(w_ + 2 * 512) = T2;                                             \
    *(short8*)(w_ + 3 * 512) = T3;                                             \
  } while (0)

#define PHASE(t_, MASKED_)                                                     \
  do {                                                                         \
    const short* rd_ = rd + ((t_) & 1) * 8192;                                 \
    const int k0_ = (t_) * KB;                                                 \
    _Pragma("unroll")                                                          \
    for (int kkh = 0; kkh < 2; ++kkh) {                                        \
      const int kk = kkh * 32;                                                 \
      if (!(MASKED_) || (q0 + wv * 32 + 31 >= k0_ + kk)) {                     \
        short8 kf[4], vf[4];                                                   \
        _Pragma("unroll")                                                      \
        for (int j = 0; j < 4; ++j) {                                          \
          kf[j] = *(const short8*)(rd_ + (kkh * 4 + j) * 512);                 \
          vf[j] = *(const short8*)(rd_ + 4096 + (kkh * 4 + j) * 512);          \
        }                                                                      \
        f32x4 stL[2], stH[2];                                                  \
        _Pragma("unroll")                                                      \
        for (int hq = 0; hq < 2; ++hq) {                                       \
          stL[hq] = onesf;                                                     \
          stH[hq] = onesf;                                                     \
          _Pragma("unroll")                                                    \
          for (int c = 0; c < 2; ++c) {                                        \
            stL[hq] = __builtin_amdgcn_mfma_f32_16x16x32_bf16(kf[c],     qf[hq][c].s, stL[hq], 0, 0, 0); \
            stH[hq] = __builtin_amdgcn_mfma_f32_16x16x32_bf16(kf[2 + c], qf[hq][c].s, stH[hq], 0, 0, 0); \
          }                                                                    \
        }                                                                      \
        unsigned wrd[2][4];                                                    \
        _Pragma("unroll")                                                      \
        for (int hq = 0; hq < 2; ++hq) {                                       \
          const int qrow = q0 + wv * 32 + hq * 16 + qid;                       \
          float pl[4], ph[4];                                                  \
          _Pragma("unroll")                                                    \
          for (int r = 0; r < 4; ++r) {                                        \
            float tl = stL[hq][r], th = stH[hq][r];                            \
            pl[r] = fmaf(tl, tl, 1.0f);   /* p' = (1+s)^2 + 1 = 2p */          \
            ph[r] = fmaf(th, th, 1.0f);                                        \
            if (MASKED_) {                                                     \
              if (k0_ + kk + 4 * g + r > qrow)      pl[r] = 0.f;               \
              if (k0_ + kk + 16 + 4 * g + r > qrow) ph[r] = 0.f;               \
            }                                                                  \
          }                                                                    \
          wrd[hq][0] = pack2(pl[0], pl[1]);                                    \
          wrd[hq][1] = pack2(pl[2], pl[3]);                                    \
          wrd[hq][2] = pack2(ph[0], ph[1]);                                    \
          wrd[hq][3] = pack2(ph[2], ph[3]);                                    \
        }                                                                      \
        Frag pa[2];                                                            \
        _Pragma("unroll")                                                      \
        for (int hq = 0; hq < 2; ++hq) {                                       \
          auto sA32 = __builtin_amdgcn_permlane32_swap(wrd[hq][0], wrd[hq][2], false, false); \
          auto sA16 = __builtin_amdgcn_permlane16_swap(sA32[0], sA32[1], false, false);       \
          auto sB32 = __builtin_amdgcn_permlane32_swap(wrd[hq][1], wrd[hq][3], false, false); \
          auto sB16 = __builtin_amdgcn_permlane16_swap(sB32[0], sB32[1], false, false);       \
          pa[hq].u[0] = (unsigned)sA16[0];                                     \
          pa[hq].u[2] = (unsigned)sA16[1];                                     \
          pa[hq].u[1] = (unsigned)sB16[0];                                     \
          pa[hq].u[3] = (unsigned)sB16[1];                                     \
        }                                                                      \
        _Pragma("unroll")                                                      \
        for (int n = 0; n < 4; ++n) {                                          \
          acc[0][n] = __builtin_amdgcn_mfma_f32_16x16x32_bf16(pa[0].s, vf[n], acc[0][n], 0, 0, 0); \
          acc[1][n] = __builtin_amdgcn_mfma_f32_16x16x32_bf16(pa[1].s, vf[n], acc[1][n], 0, 0, 0); \
        }                                                                      \
        dacc[0] = __builtin_amdgcn_mfma_f32_16x16x32_bf16(pa[0].s, ones.s, dacc[0], 0, 0, 0); \
        dacc[1] = __builtin_amdgcn_mfma_f32_16x16x32_bf16(pa[1].s, ones.s, dacc[1], 0, 0, 0); \
      }                                                                        \
    }                                                                          \
  } while (0)

__global__ __launch_bounds__(256, 4)
void based_one(const float* __restrict__ Qg, const short* __restrict__ Fr,
               float* __restrict__ Og) {
  const int tid  = threadIdx.x;
  const int lane = tid & 63;
  const int wv   = tid >> 6;
  const int qid  = lane & 15;
  const int g    = lane >> 4;

  const int bh = blockIdx.x;                 // linear%8 = bh%8 -> XCD-local
  const int qt = NQT - 1 - (int)blockIdx.y;  // heavy blocks dispatch first
  const int q0 = qt * QB;

  __shared__ __align__(16) short ring[2 * 8192];   // 2 tiles x 16 KB = 32 KB

  const size_t base = (size_t)bh * S_LEN;

  // ---- hoisted per-lane base pointers ----
  const short* gk = Fr + ((wv < 2) ? 0 : 8388608)
                    + ((size_t)(bh << 5) << 12) + (wv & 1) * 2048 + lane * 8;
  short* wr = &ring[((wv >= 2) ? 4096 : 0) + (wv & 1) * 2048 + lane * 8];
  const short* rd = &ring[lane * 8];

  Frag ones;         // bf16 ones-column for denominator MFMA
  {
    const unsigned ov = (qid == 0) ? 0x3F803F80u : 0u;
    ones.u[0] = ov; ones.u[1] = ov; ones.u[2] = ov; ones.u[3] = ov;
  }
  const f32x4 onesf = (f32x4){1.f, 1.f, 1.f, 1.f};  // QK seed -> t = 1+s

  // ---- Q fragments, pre-scaled by 1/sqrt(D)=0.125 ----
  Frag qf[2][2];
  {
    const float SC = 0.125f;
#pragma unroll
    for (int hq = 0; hq < 2; ++hq) {
      const int qrow = q0 + wv * 32 + hq * 16 + qid;
      const float* qp = Qg + (base + qrow) * DH + g * 8;
#pragma unroll
      for (int c = 0; c < 2; ++c) {
        float4 f0 = *(const float4*)(qp + c * 32);
        float4 f1 = *(const float4*)(qp + c * 32 + 4);
        qf[hq][c].u[0] = pack2(f0.x * SC, f0.y * SC);
        qf[hq][c].u[1] = pack2(f0.z * SC, f0.w * SC);
        qf[hq][c].u[2] = pack2(f1.x * SC, f1.y * SC);
        qf[hq][c].u[3] = pack2(f1.z * SC, f1.w * SC);
      }
    }
  }

  f32x4 acc[2][4];
  f32x4 dacc[2];
#pragma unroll
  for (int hq = 0; hq < 2; ++hq) {
    dacc[hq] = (f32x4){0.f, 0.f, 0.f, 0.f};
#pragma unroll
    for (int n = 0; n < 4; ++n) acc[hq][n] = (f32x4){0.f, 0.f, 0.f, 0.f};
  }

  const int nfull = 2 * qt;            // nt = nfull + 2

  short8 a0, a1, a2, a3;               // one staging buffer (distance 1)

  GLOAD2(0, a0, a1, a2, a3);
  DSWRITE2(0, a0, a1, a2, a3);
  __syncthreads();

  for (int t = 0; t < nfull; ++t) {
    GLOAD2(t + 1, a0, a1, a2, a3);     // issue early; hides under compute
    PHASE(t, 0);
    DSWRITE2(t + 1, a0, a1, a2, a3);   // write late (slot (t+1)&1, not read now)
    __syncthreads();
  }
  // masked diagonal tiles
  GLOAD2(nfull + 1, a0, a1, a2, a3);
  PHASE(nfull, 1);
  DSWRITE2(nfull + 1, a0, a1, a2, a3);
  __syncthreads();
  PHASE(nfull + 1, 1);

  // ---- normalize and store fp32 (p' = 2p: eps doubles, ratio exact) ----
#pragma unroll
  for (int hq = 0; hq < 2; ++hq) {
#pragma unroll
    for (int r = 0; r < 4; ++r) {
      float dn  = __shfl(dacc[hq][r], 16 * g);
      float inv = 1.0f / (dn + 2e-6f);
      const int row = q0 + wv * 32 + hq * 16 + 4 * g + r;
      float* op = Og + (base + row) * DH + qid;
#pragma unroll
      for (int n = 0; n < 4; ++n) op[n * 16] = acc[hq][n][r] * inv;
    }
  }
}

// =====================================================================
// Fallback (R8 kernel, verified): used only if ws_size < 32 MB.
// =====================================================================
#define STAGE_LOAD(k0_)                                                        \
  do {                                                                         \
    if (tid < 128) {                                                           \
      const float4* ksrc = (const float4*)(Kg + (base + (size_t)(k0_)) * DH); \
      r0 = ksrc[tid];       r1 = ksrc[tid + 128];                              \
      r2 = ksrc[tid + 256]; r3 = ksrc[tid + 384];                              \
      r4 = ksrc[tid + 512]; r5 = ksrc[tid + 640];                              \
      r6 = ksrc[tid + 768]; r7 = ksrc[tid + 896];                              \
    } else {                                                                   \
      const float4* vsrc = (const float4*)(Vg + (base + (size_t)(k0_)) * DH)  \
                           + ((tid - 128) >> 4) * 128 + ((tid - 128) & 15);    \
      r0 = vsrc[0];  r1 = vsrc[16]; r2 = vsrc[32]; r3 = vsrc[48];              \
      r4 = vsrc[64]; r5 = vsrc[80]; r6 = vsrc[96]; r7 = vsrc[112];             \
    }                                                                          \
  } while (0)

#define STAGE_WRITE(b_)                                                        \
  do {                                                                         \
    if (tid < 128) {                                                           \
      short* Kd = Klds[b_];                                                    \
      const int rb = tid >> 4, c4 = tid & 15;                                  \
      *(uint2*)&Kd[(rb + 0)  * LDS_STRIDE + c4 * 4] = make_uint2(pack2(r0.x, r0.y), pack2(r0.z, r0.w)); \
      *(uint2*)&Kd[(rb + 8)  * LDS_STRIDE + c4 * 4] = make_uint2(pack2(r1.x, r1.y), pack2(r1.z, r1.w)); \
      *(uint2*)&Kd[(rb + 16) * LDS_STRIDE + c4 * 4] = make_uint2(pack2(r2.x, r2.y), pack2(r2.z, r2.w)); \
      *(uint2*)&Kd[(rb + 24) * LDS_STRIDE + c4 * 4] = make_uint2(pack2(r3.x, r3.y), pack2(r3.z, r3.w)); \
      *(uint2*)&Kd[(rb + 32) * LDS_STRIDE + c4 * 4] = make_uint2(pack2(r4.x, r4.y), pack2(r4.z, r4.w)); \
      *(uint2*)&Kd[(rb + 40) * LDS_STRIDE + c4 * 4] = make_uint2(pack2(r5.x, r5.y), pack2(r5.z, r5.w)); \
      *(uint2*)&Kd[(rb + 48) * LDS_STRIDE + c4 * 4] = make_uint2(pack2(r6.x, r6.y), pack2(r6.z, r6.w)); \
      *(uint2*)&Kd[(rb + 56) * LDS_STRIDE + c4 * 4] = make_uint2(pack2(r7.x, r7.y), pack2(r7.z, r7.w)); \
    } else {                                                                   \
      short* Vd = Vlds[b_];                                                    \
      const int l = tid - 128, c4 = l & 15, rp = l >> 4;                       \
      const int slot = (rp + (c4 & 7)) & 7;                                    \
      short* vp = &Vd[(c4 * 4) * LDS_STRIDE + slot * 8];                       \
      Frag w;                                                                  \
      w.u[0] = pack2(r0.x, r1.x); w.u[1] = pack2(r2.x, r3.x);                  \
      w.u[2] = pack2(r4.x, r5.x); w.u[3] = pack2(r6.x, r7.x);                  \
      *(short8*)&vp[0 * LDS_STRIDE] = w.s;                                     \
      w.u[0] = pack2(r0.y, r1.y); w.u[1] = pack2(r2.y, r3.y);                  \
      w.u[2] = pack2(r4.y, r5.y); w.u[3] = pack2(r6.y, r7.y);                  \
      *(short8*)&vp[1 * LDS_STRIDE] = w.s;                                     \
      w.u[0] = pack2(r0.z, r1.z); w.u[1] = pack2(r2.z, r3.z);                  \
      w.u[2] = pack2(r4.z, r5.z); w.u[3] = pack2(r6.z, r7.z);                  \
      *(short8*)&vp[2 * LDS_STRIDE] = w.s;                                     \
      w.u[0] = pack2(r0.w, r1.w); w.u[1] = pack2(r2.w, r3.w);                  \
      w.u[2] = pack2(r4.w, r5.w); w.u[3] = pack2(r6.w, r7.w);                  \
      *(short8*)&vp[3 * LDS_STRIDE] = w.s;                                     \
    }                                                                          \
  } while (0)

#define COMPUTE_TILE(KbP_, VbP_, k0_, MASKED_)                                 \
  do {                                                                         \
    const short* Kb = (KbP_);                                                  \
    const short* Vb = (VbP_);                                                  \
    _Pragma("unroll")                                                          \
    for (int kk = 0; kk < KB; kk += 32) {                                      \
      if (!(MASKED_) || (q0 + wv * 32 + 31 >= (k0_) + kk)) {                   \
        short8 aLo[2], aHi[2];                                                 \
        _Pragma("unroll")                                                      \
        for (int c = 0; c < 2; ++c) {                                          \
          aLo[c] = *(const short8*)&Kb[(kk + qid) * LDS_STRIDE + c * 32 + g * 8];        \
          aHi[c] = *(const short8*)&Kb[(kk + 16 + qid) * LDS_STRIDE + c * 32 + g * 8];   \
        }                                                                      \
        f32x4 stL[2], stH[2];                                                  \
        _Pragma("unroll")                                                      \
        for (int hq = 0; hq < 2; ++hq) {                                       \
          stL[hq] = (f32x4){0.f, 0.f, 0.f, 0.f};                               \
          stH[hq] = (f32x4){0.f, 0.f, 0.f, 0.f};                               \
          _Pragma("unroll")                                                    \
          for (int c = 0; c < 2; ++c) {                                        \
            stL[hq] = __builtin_amdgcn_mfma_f32_16x16x32_bf16(aLo[c], qf[hq][c].s, stL[hq], 0, 0, 0); \
            stH[hq] = __builtin_amdgcn_mfma_f32_16x16x32_bf16(aHi[c], qf[hq][c].s, stH[hq], 0, 0, 0); \
          }                                                                    \
        }                                                                      \
        unsigned wrd[2][4];                                                    \
        _Pragma("unroll")                                                      \
        for (int hq = 0; hq < 2; ++hq) {                                       \
          const int qrow = q0 + wv * 32 + hq * 16 + qid;                       \
          float pl[4], ph[4];                                                  \
          _Pragma("unroll")                                                    \
          for (int r = 0; r < 4; ++r) {                                        \
            float sl = stL[hq][r], sh = stH[hq][r];                            \
            pl[r] = fmaf(sl, fmaf(sl, 0.5f, 1.0f), 1.0f);                      \
            ph[r] = fmaf(sh, fmaf(sh, 0.5f, 1.0f), 1.0f);                      \
            if (MASKED_) {                                                     \
              if ((k0_) + kk + 4 * g + r > qrow)      pl[r] = 0.f;             \
              if ((k0_) + kk + 16 + 4 * g + r > qrow) ph[r] = 0.f;             \
            }                                                                  \
          }                                                                    \
          wrd[hq][0] = pack2(pl[0], pl[1]);                                    \
          wrd[hq][1] = pack2(pl[2], pl[3]);                                    \
          wrd[hq][2] = pack2(ph[0], ph[1]);                                    \
          wrd[hq][3] = pack2(ph[2], ph[3]);                                    \
        }                                                                      \
        Frag pa[2];                                                            \
        _Pragma("unroll")                                                      \
        for (int hq = 0; hq < 2; ++hq) {                                       \
          auto sA32 = __builtin_amdgcn_permlane32_swap(wrd[hq][0], wrd[hq][2], false, false); \
          auto sA16 = __builtin_amdgcn_permlane16_swap(sA32[0], sA32[1], false, false);       \
          auto sB32 = __builtin_amdgcn_permlane32_swap(wrd[hq][1], wrd[hq][3], false, false); \
          auto sB16 = __builtin_amdgcn_permlane16_swap(sB32[0], sB32[1], false, false);       \
          pa[hq].u[0] = (unsigned)sA16[0];                                     \
          pa[hq].u[2] = (unsigned)sA16[1];                                     \
          pa[hq].u[1] = (unsigned)sB16[0];                                     \
          pa[hq].u[3] = (unsigned)sB16[1];                                     \
        }                                                                      \
        _Pragma("unroll")                                                      \
        for (int n = 0; n < 4; ++n) {                                          \
          const int row = n * 16 + qid;                                        \
          const int un  = ((kk >> 3) + g + ((row >> 2) & 7)) & 7;              \
          short8 vb = *(const short8*)&Vb[row * LDS_STRIDE + un * 8];          \
          acc[0][n] = __builtin_amdgcn_mfma_f32_16x16x32_bf16(pa[0].s, vb, acc[0][n], 0, 0, 0); \
          acc[1][n] = __builtin_amdgcn_mfma_f32_16x16x32_bf16(pa[1].s, vb, acc[1][n], 0, 0, 0); \
        }                                                                      \
        dacc[0] = __builtin_amdgcn_mfma_f32_16x16x32_bf16(pa[0].s, ones.s, dacc[0], 0, 0, 0);   \
        dacc[1] = __builtin_amdgcn_mfma_f32_16x16x32_bf16(pa[1].s, ones.s, dacc[1], 0, 0, 0);   \
      }                                                                        \
    }                                                                          \
  } while (0)

__global__ __launch_bounds__(256, 2)
void based_attn(const float* __restrict__ Qg,
                const float* __restrict__ Kg,
                const float* __restrict__ Vg,
                float* __restrict__ Og) {
  const int tid  = threadIdx.x;
  const int lane = tid & 63;
  const int wv   = tid >> 6;
  const int qid  = lane & 15;
  const int g    = lane >> 4;

  const int bh = blockIdx.x;
  const int qy = blockIdx.y;

  __shared__ short Klds[2][KB * LDS_STRIDE];
  __shared__ short Vlds[2][DH * LDS_STRIDE];

  const size_t base = (size_t)bh * S_LEN;

  Frag ones;
  {
    const unsigned ov = (qid == 0) ? 0x3F803F80u : 0u;
    ones.u[0] = ov; ones.u[1] = ov; ones.u[2] = ov; ones.u[3] = ov;
  }

  float4 r0, r1, r2, r3, r4, r5, r6, r7;

#pragma unroll 1
  for (int half = 0; half < 2; ++half) {
    const int qt = half ? (NQT - 1 - qy) : qy;
    const int q0 = qt * QB;

    Frag qf[2][2];
    {
      const float SC = 0.125f;
#pragma unroll
      for (int hq = 0; hq < 2; ++hq) {
        const int qrow = q0 + wv * 32 + hq * 16 + qid;
        const float* qp = Qg + (base + qrow) * DH + g * 8;
#pragma unroll
        for (int c = 0; c < 2; ++c) {
          float4 f0 = *(const float4*)(qp + c * 32);
          float4 f1 = *(const float4*)(qp + c * 32 + 4);
          qf[hq][c].u[0] = pack2(f0.x * SC, f0.y * SC);
          qf[hq][c].u[1] = pack2(f0.z * SC, f0.w * SC);
          qf[hq][c].u[2] = pack2(f1.x * SC, f1.y * SC);
          qf[hq][c].u[3] = pack2(f1.z * SC, f1.w * SC);
        }
      }
    }

    f32x4 acc[2][4];
    f32x4 dacc[2];
#pragma unroll
    for (int hq = 0; hq < 2; ++hq) {
      dacc[hq] = (f32x4){0.f, 0.f, 0.f, 0.f};
#pragma unroll
      for (int n = 0; n < 4; ++n) acc[hq][n] = (f32x4){0.f, 0.f, 0.f, 0.f};
    }

    STAGE_LOAD(0);
    STAGE_WRITE(0);
    __syncthreads();

    const int nfull = 2 * qt;
    for (int t = 0; t < nfull; ++t) {
      STAGE_LOAD((t + 1) * KB);
      COMPUTE_TILE(Klds[t & 1], Vlds[t & 1], t * KB, 0);
      STAGE_WRITE((t + 1) & 1);
      __syncthreads();
    }
    {
      int t = nfull;
      STAGE_LOAD((t + 1) * KB);
      COMPUTE_TILE(Klds[t & 1], Vlds[t & 1], t * KB, 1);
      STAGE_WRITE((t + 1) & 1);
      __syncthreads();
      t = nfull + 1;
      COMPUTE_TILE(Klds[t & 1], Vlds[t & 1], t * KB, 1);
    }

#pragma unroll
    for (int hq = 0; hq < 2; ++hq) {
#pragma unroll
      for (int r = 0; r < 4; ++r) {
        float dn  = __shfl(dacc[hq][r], 16 * g);
        float inv = 1.0f / (dn + 1e-6f);
        const int row = q0 + wv * 32 + hq * 16 + 4 * g + r;
        float* op = Og + (base + row) * DH + qid;
#pragma unroll
        for (int n = 0; n < 4; ++n) op[n * 16] = acc[hq][n][r] * inv;
      }
    }
  }
}

extern "C" void kernel_launch(void* const* d_in, const int* in_sizes, int n_in,
                              void* d_out, int out_size, void* d_ws, size_t ws_size,
                              hipStream_t stream) {
  (void)in_sizes; (void)n_in; (void)out_size;
  const float* Q = (const float*)d_in[0];
  const float* K = (const float*)d_in[1];
  const float* V = (const float*)d_in[2];
  float* O = (float*)d_out;

  if (ws_size >= (size_t)33554432) {
    short* ws = (short*)d_ws;
    repack<<<dim3(2048), 256, 0, stream>>>(K, V, ws);
    based_one<<<dim3(64, 16), 256, 0, stream>>>(Q, ws, O);
  } else {
    dim3 grid(BHN, NQT / 2);
    based_attn<<<grid, 256, 0, stream>>>(Q, K, V, O);
  }
}